// Round 1
// baseline (3308.794 us; speedup 1.0000x reference)
//
#include <hip/hip_runtime.h>
#include <stdint.h>

#define EPSV 1e-5f

// ---------------------------------------------------------------------------
// Weight quantization: per-tensor s = max|w|/7, q = clip(rint(w/s), -7, 7)
// One block per tensor (n <= 36864).
// ---------------------------------------------------------------------------
__global__ __launch_bounds__(256) void k_quant_weight(
    const float* __restrict__ w, int n, int8_t* __restrict__ qw,
    float* __restrict__ s_out)
{
    __shared__ float red[256];
    float m = 0.f;
    for (int i = threadIdx.x; i < n; i += 256) m = fmaxf(m, fabsf(w[i]));
    red[threadIdx.x] = m;
    __syncthreads();
    for (int s = 128; s > 0; s >>= 1) {
        if (threadIdx.x < s) red[threadIdx.x] = fmaxf(red[threadIdx.x], red[threadIdx.x + s]);
        __syncthreads();
    }
    float scale = red[0] / 7.0f;
    if (threadIdx.x == 0) *s_out = scale;
    for (int i = threadIdx.x; i < n; i += 256) {
        float r = rintf(w[i] / scale);
        r = fminf(fmaxf(r, -7.f), 7.f);
        qw[i] = (int8_t)(int)r;
    }
}

// ---------------------------------------------------------------------------
// BatchNorm precompute: inv = g/sqrt(v+eps), beta = b - m*inv
// bn layout: (4, C) stacked [g, b, m, v]. 8 blocks, one per layer.
// Output: bnp[layer*128 + c] = inv, bnp[layer*128 + 64 + c] = beta
// ---------------------------------------------------------------------------
struct BnArgs {
    const float* bn[8];
    int C[8];
    float* outp;
};

__global__ __launch_bounds__(64) void k_bn(BnArgs a)
{
#pragma clang fp contract(off)
    int l = blockIdx.x;
    int c = threadIdx.x;
    int C = a.C[l];
    if (c < C) {
        const float* bn = a.bn[l];
        float g = bn[c], b = bn[C + c], m = bn[2 * C + c], v = bn[3 * C + c];
        float inv = g / sqrtf(v + EPSV);
        float mi = m * inv;
        a.outp[l * 128 + c] = inv;
        a.outp[l * 128 + 64 + c] = b - mi;
    }
}

// ---------------------------------------------------------------------------
// Input double fake-quant: fq(x, s0, -8, 7) then fq(., s1, -8, 7) -> int8
// ---------------------------------------------------------------------------
__global__ __launch_bounds__(256) void k_quant_input(
    const float* __restrict__ x, int8_t* __restrict__ q, int n,
    const float* __restrict__ scales)
{
#pragma clang fp contract(off)
    int i = blockIdx.x * 256 + threadIdx.x;
    if (i >= n) return;
    float s0 = scales[0], s1 = scales[1];
    float r = rintf(x[i] / s0);
    r = fminf(fmaxf(r, -8.f), 7.f);
    float v = r * s0;
    float r2 = rintf(v / s1);
    r2 = fminf(fmaxf(r2, -8.f), 7.f);
    q[i] = (int8_t)(int)r2;
}

// ---------------------------------------------------------------------------
// Quant epilogue helpers (contract off: match numpy's mul-then-add rounding)
// ---------------------------------------------------------------------------
__device__ __forceinline__ int q_relu_u4(float sum, float fscale, float inv,
                                         float beta, float s_relu)
{
#pragma clang fp contract(off)
    float y = sum * fscale;   // conv result in float domain
    y = y * inv;
    y = y + beta;             // BatchNorm
    float r = rintf(y / s_relu);
    r = fminf(fmaxf(r, 0.f), 15.f);   // ReLU + unsigned int4 quant
    return (int)r;
}

__device__ __forceinline__ int8_t requant_s4(int q, float s_relu, float s_next)
{
#pragma clang fp contract(off)
    float v = (float)q * s_relu;      // dequantized value as stored by ref
    float r = rintf(v / s_next);
    r = fminf(fmaxf(r, -8.f), 7.f);   // next layer's signed int4 input quant
    return (int8_t)(int)r;
}

// ---------------------------------------------------------------------------
// Fused block: 3x3 conv (int math, exact) + BN + ReLU-quant + (maxpool) +
// requant with next layer's input scale. Templated on CIN and POOL.
// grid: (ceil(Ho*Wo/256), Co, B). Weights for this co staged in LDS as float.
// ---------------------------------------------------------------------------
template <int CIN, bool POOL>
__global__ __launch_bounds__(256) void k_conv_block(
    const int8_t* __restrict__ in, int8_t* __restrict__ out,
    const int8_t* __restrict__ wq,      // [Co][CIN][3][3]
    const float* __restrict__ scales,
    const float* __restrict__ swq,      // per-layer weight scales [9]
    const float* __restrict__ bnp,      // this layer: inv at [co], beta at [64+co]
    int H, int W, int layer, int sin_idx, int srelu_idx, int snext_idx)
{
    __shared__ float wsh[CIN * 9];
    const int co = blockIdx.y;
    const int b  = blockIdx.z;
    const int Co = gridDim.y;

    for (int i = threadIdx.x; i < CIN * 9; i += 256)
        wsh[i] = (float)wq[co * CIN * 9 + i];
    __syncthreads();

    const int Ho = POOL ? H / 2 : H;
    const int Wo = POOL ? W / 2 : W;
    const int sp = blockIdx.x * 256 + threadIdx.x;
    if (sp >= Ho * Wo) return;
    const int py = sp / Wo;
    const int px = sp % Wo;

    const float fscale = scales[sin_idx] * swq[layer];
    const float inv    = bnp[co];
    const float beta   = bnp[64 + co];
    const float s_relu = scales[srelu_idx];
    const float s_next = scales[snext_idx];

    int qmax;
    if (POOL) {
        float acc0 = 0.f, acc1 = 0.f, acc2 = 0.f, acc3 = 0.f;
        const int iy0 = 2 * py - 1;
        const int ix0 = 2 * px - 1;
        for (int ci = 0; ci < CIN; ci++) {
            const int8_t* ip = in + (size_t)(b * CIN + ci) * H * W;
            float a[4][4];
#pragma unroll
            for (int r = 0; r < 4; r++) {
                const int iy = iy0 + r;
                const bool ry = (unsigned)iy < (unsigned)H;
#pragma unroll
                for (int c = 0; c < 4; c++) {
                    const int ix = ix0 + c;
                    a[r][c] = (ry && (unsigned)ix < (unsigned)W)
                                  ? (float)ip[iy * W + ix] : 0.f;
                }
            }
            const float* wp = &wsh[ci * 9];
#pragma unroll
            for (int ky = 0; ky < 3; ky++)
#pragma unroll
                for (int kx = 0; kx < 3; kx++) {
                    const float wv = wp[ky * 3 + kx];
                    acc0 += wv * a[ky][kx];
                    acc1 += wv * a[ky][kx + 1];
                    acc2 += wv * a[ky + 1][kx];
                    acc3 += wv * a[ky + 1][kx + 1];
                }
        }
        int q0 = q_relu_u4(acc0, fscale, inv, beta, s_relu);
        int q1 = q_relu_u4(acc1, fscale, inv, beta, s_relu);
        int q2 = q_relu_u4(acc2, fscale, inv, beta, s_relu);
        int q3 = q_relu_u4(acc3, fscale, inv, beta, s_relu);
        qmax = max(max(q0, q1), max(q2, q3));
    } else {
        float acc = 0.f;
        const int iy0 = py - 1;
        const int ix0 = px - 1;
        for (int ci = 0; ci < CIN; ci++) {
            const int8_t* ip = in + (size_t)(b * CIN + ci) * H * W;
            float a[3][3];
#pragma unroll
            for (int r = 0; r < 3; r++) {
                const int iy = iy0 + r;
                const bool ry = (unsigned)iy < (unsigned)H;
#pragma unroll
                for (int c = 0; c < 3; c++) {
                    const int ix = ix0 + c;
                    a[r][c] = (ry && (unsigned)ix < (unsigned)W)
                                  ? (float)ip[iy * W + ix] : 0.f;
                }
            }
            const float* wp = &wsh[ci * 9];
#pragma unroll
            for (int ky = 0; ky < 3; ky++)
#pragma unroll
                for (int kx = 0; kx < 3; kx++)
                    acc += wp[ky * 3 + kx] * a[ky][kx];
        }
        qmax = q_relu_u4(acc, fscale, inv, beta, s_relu);
    }

    out[(size_t)(b * Co + co) * (Ho * Wo) + sp] = requant_s4(qmax, s_relu, s_next);
}

// ---------------------------------------------------------------------------
// Head: 1x1 conv (64 -> 36) + bias, fp32 out.
// grid: (ceil(800/256), 36, 16)
// ---------------------------------------------------------------------------
__global__ __launch_bounds__(256) void k_head(
    const int8_t* __restrict__ in,   // [16][64][800], ints in [0,7]
    float* __restrict__ out,         // [16][36][800]
    const int8_t* __restrict__ wq,   // [36][64]
    const float* __restrict__ scales,
    const float* __restrict__ swq,
    const float* __restrict__ b9)
{
#pragma clang fp contract(off)
    __shared__ float wsh[64];
    const int co = blockIdx.y;
    const int b  = blockIdx.z;
    if (threadIdx.x < 64) wsh[threadIdx.x] = (float)wq[co * 64 + threadIdx.x];
    __syncthreads();
    const int p = blockIdx.x * 256 + threadIdx.x;
    if (p >= 800) return;
    const int8_t* ip = in + (size_t)b * 64 * 800 + p;
    float acc = 0.f;
#pragma unroll
    for (int ci = 0; ci < 64; ci++) acc += wsh[ci] * (float)ip[ci * 800];
    float fs = scales[9] * swq[8];
    float y = acc * fs;
    out[(size_t)(b * 36 + co) * 800 + p] = y + b9[co];
}

// ---------------------------------------------------------------------------
// Launch
// ---------------------------------------------------------------------------
extern "C" void kernel_launch(void* const* d_in, const int* in_sizes, int n_in,
                              void* d_out, int out_size, void* d_ws, size_t ws_size,
                              hipStream_t stream)
{
    const float* x = (const float*)d_in[0];
    const float* w[9];
    for (int i = 0; i < 9; i++) w[i] = (const float*)d_in[1 + i];
    const float* b9 = (const float*)d_in[10];
    const float* bn[8];
    for (int i = 0; i < 8; i++) bn[i] = (const float*)d_in[11 + i];
    const float* scales = (const float*)d_in[19];

    // workspace layout
    int8_t* ws8   = (int8_t*)d_ws;
    int8_t* bufA  = ws8;                         // max use: 9,830,400 B (quant input)
    int8_t* bufB  = ws8 + (10u << 20);           // max use: 13,107,200 B (block0 out)
    int8_t* qwb   = ws8 + (24u << 20);           // quantized weights (~210 KB)
    float*  swq   = (float*)(ws8 + (24u << 20) + (256u << 10));  // 9 scales
    float*  bnp   = (float*)(ws8 + (24u << 20) + (256u << 10) + 256); // 8*128 floats

    static const int wn[9] = {432, 4608, 18432, 36864, 36864, 36864, 36864, 36864, 2304};
    static const int wo[9] = {0, 512, 5120, 23552, 60416, 97280, 134144, 171008, 207872};

    // 1) quantize weights
    for (int i = 0; i < 9; i++)
        k_quant_weight<<<1, 256, 0, stream>>>(w[i], wn[i], qwb + wo[i], swq + i);

    // 2) BN precompute
    BnArgs ba;
    static const int chans[8] = {16, 32, 64, 64, 64, 64, 64, 64};
    for (int i = 0; i < 8; i++) { ba.bn[i] = bn[i]; ba.C[i] = chans[i]; }
    ba.outp = bnp;
    k_bn<<<8, 64, 0, stream>>>(ba);

    // 3) input double-quant -> int8
    const int n_in_elems = 16 * 3 * 320 * 640;
    k_quant_input<<<(n_in_elems + 255) / 256, 256, 0, stream>>>(x, bufA, n_in_elems, scales);

    // 4) fused blocks (ping-pong A/B)
    // layer 0: CIN=3, Co=16, 320x640 -> 160x320 (pool)
    k_conv_block<3, true><<<dim3(200, 16, 16), 256, 0, stream>>>(
        bufA, bufB, qwb + wo[0], scales, swq, bnp + 0 * 128, 320, 640, 0, 1, 10, 2);
    // layer 1: CIN=16, Co=32, 160x320 -> 80x160
    k_conv_block<16, true><<<dim3(50, 32, 16), 256, 0, stream>>>(
        bufB, bufA, qwb + wo[1], scales, swq, bnp + 1 * 128, 160, 320, 1, 2, 11, 3);
    // layer 2: CIN=32, Co=64, 80x160 -> 40x80
    k_conv_block<32, true><<<dim3(13, 64, 16), 256, 0, stream>>>(
        bufA, bufB, qwb + wo[2], scales, swq, bnp + 2 * 128, 80, 160, 2, 3, 12, 4);
    // layer 3: CIN=64, Co=64, 40x80 -> 20x40
    k_conv_block<64, true><<<dim3(4, 64, 16), 256, 0, stream>>>(
        bufB, bufA, qwb + wo[3], scales, swq, bnp + 3 * 128, 40, 80, 3, 4, 13, 5);
    // layers 4-7: CIN=64, Co=64, 20x40 (no pool)
    k_conv_block<64, false><<<dim3(4, 64, 16), 256, 0, stream>>>(
        bufA, bufB, qwb + wo[4], scales, swq, bnp + 4 * 128, 20, 40, 4, 5, 14, 6);
    k_conv_block<64, false><<<dim3(4, 64, 16), 256, 0, stream>>>(
        bufB, bufA, qwb + wo[5], scales, swq, bnp + 5 * 128, 20, 40, 5, 6, 15, 7);
    k_conv_block<64, false><<<dim3(4, 64, 16), 256, 0, stream>>>(
        bufA, bufB, qwb + wo[6], scales, swq, bnp + 6 * 128, 20, 40, 6, 7, 16, 8);
    k_conv_block<64, false><<<dim3(4, 64, 16), 256, 0, stream>>>(
        bufB, bufA, qwb + wo[7], scales, swq, bnp + 7 * 128, 20, 40, 7, 8, 17, 9);

    // 5) head: 1x1 conv + bias -> fp32 out
    k_head<<<dim3(4, 36, 16), 256, 0, stream>>>(
        bufA, (float*)d_out, qwb + wo[8], scales, swq, b9);

    (void)in_sizes; (void)n_in; (void)out_size; (void)ws_size;
}

// Round 2
// 379.629 us; speedup vs baseline: 8.7159x; 8.7159x over previous
//
#include <hip/hip_runtime.h>
#include <stdint.h>

#define EPSV 1e-5f

// ---------------------------------------------------------------------------
// int8x4 dot product: c + sum_i sext(a.b[i])*sext(b.b[i])
// ---------------------------------------------------------------------------
__device__ __forceinline__ int dot4(int a, int b, int c) {
#if __has_builtin(__builtin_amdgcn_sdot4)
    return __builtin_amdgcn_sdot4(a, b, c, false);
#else
    int r = c;
#pragma unroll
    for (int i = 0; i < 4; ++i)
        r += ((int)(int8_t)(a >> (8 * i))) * ((int)(int8_t)(b >> (8 * i)));
    return r;
#endif
}

// ---------------------------------------------------------------------------
// Quant epilogue helpers (contract off: match numpy mul-then-add rounding)
// ---------------------------------------------------------------------------
__device__ __forceinline__ int q_relu_u4(int sum, float fscale, float inv,
                                         float beta, float s_relu)
{
#pragma clang fp contract(off)
    float y = (float)sum * fscale;    // conv result in float domain (exact int)
    y = y * inv;
    y = y + beta;                     // BatchNorm
    float r = rintf(y / s_relu);
    r = fminf(fmaxf(r, 0.f), 15.f);   // ReLU + unsigned int4 quant
    return (int)r;
}

__device__ __forceinline__ int8_t requant_s4(int q, float s_relu, float s_next)
{
#pragma clang fp contract(off)
    float v = (float)q * s_relu;      // dequantized value as stored by ref
    float r = rintf(v / s_next);
    r = fminf(fmaxf(r, -8.f), 7.f);   // next layer's signed int4 input quant
    return (int8_t)(int)r;
}

// ---------------------------------------------------------------------------
// Per-tensor weight max-abs (atomicMax on float bits; floats >= 0)
// grid: (16, 9)
// ---------------------------------------------------------------------------
struct WPtrs { const float* w[9]; int n[9]; };

__global__ __launch_bounds__(256) void k_wmax(WPtrs a, unsigned* __restrict__ smax)
{
    const int t = blockIdx.y;
    const int n = a.n[t];
    const float* w = a.w[t];
    float m = 0.f;
    for (int i = blockIdx.x * 256 + threadIdx.x; i < n; i += 16 * 256)
        m = fmaxf(m, fabsf(w[i]));
#pragma unroll
    for (int off = 32; off > 0; off >>= 1) m = fmaxf(m, __shfl_down(m, off));
    __shared__ float red[4];
    if ((threadIdx.x & 63) == 0) red[threadIdx.x >> 6] = m;
    __syncthreads();
    if (threadIdx.x == 0) {
        m = fmaxf(fmaxf(red[0], red[1]), fmaxf(red[2], red[3]));
        atomicMax(smax + t, __float_as_uint(m));
    }
}

// ---------------------------------------------------------------------------
// Prep kernel: (a) quantize+pack weights into [tap][cig][co] dwords,
// (b) BN precompute, (c) input double fake-quant -> NHWC int8x4.
// ---------------------------------------------------------------------------
struct PrepArgs {
    const float* w[9];
    const float* bn[8];
    const float* x;
    const float* scales;
    const unsigned* smax;
    int* qw;      // packed weight dwords (52560)
    float* bnp;   // 8 * 128 floats
    int* a0;      // A0: [16][320][640] dwords (4 int8 ch)
};

#define NB_PACK 206
#define NB_BN   2
#define NB_INQ  12800

__global__ __launch_bounds__(256) void k_prep(PrepArgs a)
{
#pragma clang fp contract(off)
    const int blk = blockIdx.x;
    if (blk < NB_PACK) {
        const int u = blk * 256 + threadIdx.x;
        if (u >= 52560) return;
        const int cum[10] = {0, 144, 1296, 5904, 15120, 24336, 33552, 42768, 51984, 52560};
        const int CoA[9]  = {16, 32, 64, 64, 64, 64, 64, 64, 36};
        const int CinA[9] = {3, 16, 32, 64, 64, 64, 64, 64, 64};
        const int KKA[9]  = {9, 9, 9, 9, 9, 9, 9, 9, 1};
        int t = 0;
        while (u >= cum[t + 1]) ++t;
        const int ul = u - cum[t];
        const int Co = CoA[t], CIN = CinA[t], KK = KKA[t];
        const int CIG = (CIN + 3) >> 2;
        const int co = ul % Co;
        const int r  = ul / Co;
        const int cig = r % CIG;
        const int tap = r / CIG;
        const float s = __uint_as_float(a.smax[t]) / 7.0f;
        const float* w = a.w[t];
        unsigned dw = 0;
#pragma unroll
        for (int j = 0; j < 4; ++j) {
            const int ci = 4 * cig + j;
            int q = 0;
            if (ci < CIN) {
                float rr = rintf(w[(co * CIN + ci) * KK + tap] / s);
                rr = fminf(fmaxf(rr, -7.f), 7.f);
                q = (int)rr;
            }
            dw |= ((unsigned)(q & 0xff)) << (8 * j);
        }
        a.qw[u] = (int)dw;
    } else if (blk < NB_PACK + NB_BN) {
        const int id = (blk - NB_PACK) * 256 + threadIdx.x;
        if (id >= 512) return;
        const int l = id >> 6, c = id & 63;
        const int C[8] = {16, 32, 64, 64, 64, 64, 64, 64};
        if (c < C[l]) {
            const float* bn = a.bn[l];
            const int Cl = C[l];
            float g = bn[c], b = bn[Cl + c], m = bn[2 * Cl + c], v = bn[3 * Cl + c];
            float inv = g / sqrtf(v + EPSV);
            float mi = m * inv;
            a.bnp[l * 128 + c] = inv;
            a.bnp[l * 128 + 64 + c] = b - mi;
        }
    } else {
        const int p = (blk - NB_PACK - NB_BN) * 256 + threadIdx.x;  // < 3,276,800
        const int HW = 320 * 640;
        const int b = p / HW;
        const int rest = p - b * HW;
        const float s0 = a.scales[0], s1 = a.scales[1];
        unsigned dw = 0;
#pragma unroll
        for (int ci = 0; ci < 3; ++ci) {
            float xv = a.x[(b * 3 + ci) * HW + rest];
            float r = rintf(xv / s0);
            r = fminf(fmaxf(r, -8.f), 7.f);
            float v = r * s0;
            float r2 = rintf(v / s1);
            r2 = fminf(fmaxf(r2, -8.f), 7.f);
            int q = (int)r2;
            dw |= ((unsigned)(q & 0xff)) << (8 * ci);
        }
        a.a0[p] = (int)dw;
    }
}

// ---------------------------------------------------------------------------
// Fused conv block, int8 NHWC, sdot4.
//   in : NHWC [16][H][W][CIG*4] int8
//   out: NHWC [16][Ho][Wo][CO]  int8 (requantized for next layer)
//   wq : packed dwords, index (tap*CIG + cig)*CO + co
// Block computes TH x TW output px for all CO, one image.
// thread = (co chunk of CO_T, one output px). LDS: planar input tile + weights.
// ---------------------------------------------------------------------------
template <int CIG, int CO, int CO_T, int TH, int TW, bool POOL, int H, int W>
__global__ __launch_bounds__(256) void k_conv(
    const int8_t* __restrict__ in, int8_t* __restrict__ out,
    const int* __restrict__ wq, const float* __restrict__ scales,
    const unsigned* __restrict__ smax, const float* __restrict__ bnp,
    int layer, int sin_idx, int srelu_idx, int snext_idx)
{
    constexpr int NPX = TH * TW;
    constexpr int CHUNKS = 256 / NPX;
    static_assert(CHUNKS * CO_T == CO, "chunking mismatch");
    constexpr int S = POOL ? 2 : 1;
    constexpr int IN_TH = S * TH + 2;
    constexpr int IN_TW = S * TW + 2;
    constexpr int PLANE = (IN_TH * IN_TW) | 1;   // odd stride: conflict-free
    constexpr int NACC = POOL ? 4 : 1;
    constexpr int PS = POOL ? 4 : 3;
    constexpr int Ho = POOL ? H / 2 : H;
    constexpr int Wo = POOL ? W / 2 : W;

    __shared__ int tile[CIG * PLANE];
    __shared__ int wl[9 * CIG * CO];

    const int b = blockIdx.z;
    const int gy0 = S * (blockIdx.y * TH) - 1;
    const int gx0 = S * (blockIdx.x * TW) - 1;
    const int* gin = (const int*)in;

    for (int i = threadIdx.x; i < IN_TH * IN_TW * CIG; i += 256) {
        const int cig = i & (CIG - 1);
        const int rest = i / CIG;
        const int tx = rest % IN_TW;
        const int ty = rest / IN_TW;
        const int gy = gy0 + ty, gx = gx0 + tx;
        int v = 0;
        if ((unsigned)gy < (unsigned)H && (unsigned)gx < (unsigned)W)
            v = gin[((b * H + gy) * W + gx) * CIG + cig];
        tile[cig * PLANE + ty * IN_TW + tx] = v;
    }
    {
        const int4* s4 = (const int4*)wq;
        int4* d4 = (int4*)wl;
        for (int i = threadIdx.x; i < 9 * CIG * CO / 4; i += 256) d4[i] = s4[i];
    }
    __syncthreads();

    const int chunk = threadIdx.x / NPX;
    const int pix = threadIdx.x % NPX;
    const int pyl = pix / TW;
    const int pxl = pix % TW;
    const int co0 = chunk * CO_T;

    int acc[NACC][CO_T];
#pragma unroll
    for (int k = 0; k < NACC; ++k)
#pragma unroll
        for (int j = 0; j < CO_T; ++j) acc[k][j] = 0;

    for (int cig = 0; cig < CIG; ++cig) {
        int p[PS][PS];
        const int tb = cig * PLANE + (S * pyl) * IN_TW + S * pxl;
#pragma unroll
        for (int r = 0; r < PS; ++r)
#pragma unroll
            for (int c = 0; c < PS; ++c) p[r][c] = tile[tb + r * IN_TW + c];
#pragma unroll
        for (int tap = 0; tap < 9; ++tap) {
            const int ky = tap / 3, kx = tap % 3;
            int wv[CO_T];
            const int* wp = &wl[(tap * CIG + cig) * CO + co0];
#pragma unroll
            for (int j4 = 0; j4 < CO_T / 4; ++j4)
                *(int4*)&wv[4 * j4] = *(const int4*)&wp[4 * j4];
#pragma unroll
            for (int j = 0; j < CO_T; ++j) {
                if (POOL) {
#pragma unroll
                    for (int r = 0; r < 2; ++r)
#pragma unroll
                        for (int c = 0; c < 2; ++c)
                            acc[r * 2 + c][j] = dot4(p[ky + r][kx + c], wv[j], acc[r * 2 + c][j]);
                } else {
                    acc[0][j] = dot4(p[ky][kx], wv[j], acc[0][j]);
                }
            }
        }
    }

    // epilogue: BN + ReLU-quant (+pool) + requant, store CO_T bytes
    const float swv = __uint_as_float(smax[layer]) / 7.0f;
    const float fscale = scales[sin_idx] * swv;
    const float s_relu = scales[srelu_idx];
    const float s_next = scales[snext_idx];
    const int py = blockIdx.y * TH + pyl;
    const int px = blockIdx.x * TW + pxl;

    alignas(16) int8_t obytes[CO_T];
#pragma unroll
    for (int j = 0; j < CO_T; ++j) {
        const float inv  = bnp[layer * 128 + co0 + j];
        const float beta = bnp[layer * 128 + 64 + co0 + j];
        int qmax = q_relu_u4(acc[0][j], fscale, inv, beta, s_relu);
#pragma unroll
        for (int k = 1; k < NACC; ++k)
            qmax = max(qmax, q_relu_u4(acc[k][j], fscale, inv, beta, s_relu));
        obytes[j] = requant_s4(qmax, s_relu, s_next);
    }
    int8_t* po = out + ((size_t)((b * Ho + py) * Wo + px)) * CO + co0;
    if (CO_T == 16)      *(int4*)po = *(const int4*)obytes;
    else                 *(int2*)po = *(const int2*)obytes;
}

// ---------------------------------------------------------------------------
// Head: 1x1 conv 64->36 + bias, fp32 NCHW out. grid (4, 16)
// ---------------------------------------------------------------------------
__global__ __launch_bounds__(256) void k_head(
    const int8_t* __restrict__ in,   // NHWC [16][20][40][64]
    float* __restrict__ out,         // NCHW [16][36][800]
    const int* __restrict__ wq,      // [cig*36 + co] dwords
    const float* __restrict__ scales,
    const unsigned* __restrict__ smax,
    const float* __restrict__ b9)
{
#pragma clang fp contract(off)
    __shared__ int wl[576];
    {
        for (int i = threadIdx.x; i < 576; i += 256) wl[i] = wq[i];
    }
    __syncthreads();
    const int px = blockIdx.x * 256 + threadIdx.x;
    const int b = blockIdx.y;
    if (px >= 800) return;
    const int* ip = (const int*)in + (size_t)(b * 800 + px) * 16;
    int p[16];
#pragma unroll
    for (int c4 = 0; c4 < 4; ++c4) *(int4*)&p[4 * c4] = *(const int4*)&ip[4 * c4];
    const float fs = scales[9] * (__uint_as_float(smax[8]) / 7.0f);
    for (int co = 0; co < 36; ++co) {
        int acc = 0;
#pragma unroll
        for (int cig = 0; cig < 16; ++cig) acc = dot4(p[cig], wl[cig * 36 + co], acc);
        float y = (float)acc * fs;
        out[(size_t)(b * 36 + co) * 800 + px] = y + b9[co];
    }
}

// ---------------------------------------------------------------------------
// Launch
// ---------------------------------------------------------------------------
extern "C" void kernel_launch(void* const* d_in, const int* in_sizes, int n_in,
                              void* d_out, int out_size, void* d_ws, size_t ws_size,
                              hipStream_t stream)
{
    const float* x = (const float*)d_in[0];
    const float* w[9];
    for (int i = 0; i < 9; i++) w[i] = (const float*)d_in[1 + i];
    const float* b9 = (const float*)d_in[10];
    const float* bn[8];
    for (int i = 0; i < 8; i++) bn[i] = (const float*)d_in[11 + i];
    const float* scales = (const float*)d_in[19];

    // workspace layout (total ~25.2 MiB)
    int8_t* base = (int8_t*)d_ws;
    int8_t* bufA = base;                             // 13,107,200 B
    int8_t* bufB = base + 13107200;                  // 13,107,200 B
    int*     qw  = (int*)(base + 26214400);          // 52560 dwords
    unsigned* smax = (unsigned*)(base + 26424832);   // 9 uints
    float*   bnp = (float*)(base + 26425344);        // 1024 floats

    static const int wn[9] = {432, 4608, 18432, 36864, 36864, 36864, 36864, 36864, 2304};
    // packed dword offsets per layer
    static const int qo[9] = {0, 144, 1296, 5904, 15120, 24336, 33552, 42768, 51984};

    hipMemsetAsync(smax, 0, 9 * sizeof(unsigned), stream);

    WPtrs wp;
    for (int i = 0; i < 9; i++) { wp.w[i] = w[i]; wp.n[i] = wn[i]; }
    k_wmax<<<dim3(16, 9), 256, 0, stream>>>(wp, smax);

    PrepArgs pa;
    for (int i = 0; i < 9; i++) pa.w[i] = w[i];
    for (int i = 0; i < 8; i++) pa.bn[i] = bn[i];
    pa.x = x; pa.scales = scales; pa.smax = smax;
    pa.qw = qw; pa.bnp = bnp; pa.a0 = (int*)bufA;
    k_prep<<<NB_PACK + NB_BN + NB_INQ, 256, 0, stream>>>(pa);

    // fused conv blocks (ping-pong A/B), NHWC int8
    k_conv<1, 16, 16, 8, 32, true, 320, 640><<<dim3(10, 20, 16), 256, 0, stream>>>(
        bufA, bufB, qw + qo[0], scales, smax, bnp, 0, 1, 10, 2);
    k_conv<4, 32, 16, 8, 16, true, 160, 320><<<dim3(10, 10, 16), 256, 0, stream>>>(
        bufB, bufA, qw + qo[1], scales, smax, bnp, 1, 2, 11, 3);
    k_conv<8, 64, 16, 8, 8, true, 80, 160><<<dim3(10, 5, 16), 256, 0, stream>>>(
        bufA, bufB, qw + qo[2], scales, smax, bnp, 2, 3, 12, 4);
    k_conv<16, 64, 8, 4, 8, true, 40, 80><<<dim3(5, 5, 16), 256, 0, stream>>>(
        bufB, bufA, qw + qo[3], scales, smax, bnp, 3, 4, 13, 5);
    k_conv<16, 64, 8, 4, 8, false, 20, 40><<<dim3(5, 5, 16), 256, 0, stream>>>(
        bufA, bufB, qw + qo[4], scales, smax, bnp, 4, 5, 14, 6);
    k_conv<16, 64, 8, 4, 8, false, 20, 40><<<dim3(5, 5, 16), 256, 0, stream>>>(
        bufB, bufA, qw + qo[5], scales, smax, bnp, 5, 6, 15, 7);
    k_conv<16, 64, 8, 4, 8, false, 20, 40><<<dim3(5, 5, 16), 256, 0, stream>>>(
        bufA, bufB, qw + qo[6], scales, smax, bnp, 6, 7, 16, 8);
    k_conv<16, 64, 8, 4, 8, false, 20, 40><<<dim3(5, 5, 16), 256, 0, stream>>>(
        bufB, bufA, qw + qo[7], scales, smax, bnp, 7, 8, 17, 9);

    k_head<<<dim3(4, 16), 256, 0, stream>>>(
        bufA, (float*)d_out, qw + qo[8], scales, smax, b9);

    (void)in_sizes; (void)n_in; (void)out_size; (void)ws_size;
}

// Round 3
// 221.181 us; speedup vs baseline: 14.9597x; 1.7164x over previous
//
#include <hip/hip_runtime.h>
#include <stdint.h>

#define EPSV 1e-5f

typedef int v4i __attribute__((ext_vector_type(4)));

__device__ __forceinline__ v4i mfma16(v4i a, v4i b, v4i c) {
    return __builtin_amdgcn_mfma_i32_16x16x64_i8(a, b, c, 0, 0, 0);
}

__device__ __forceinline__ int dot4(int a, int b, int c) {
#if __has_builtin(__builtin_amdgcn_sdot4)
    return __builtin_amdgcn_sdot4(a, b, c, false);
#else
    int r = c;
#pragma unroll
    for (int i = 0; i < 4; ++i)
        r += ((int)(int8_t)(a >> (8 * i))) * ((int)(int8_t)(b >> (8 * i)));
    return r;
#endif
}

// epilogue: BN + ReLU-u4-quant + requant to next layer's signed-4 code.
// (called on the pool-max of raw int accs; valid since inv>0 => monotone)
__device__ __forceinline__ int8_t q_epi(int s, float fscale, float inv, float beta,
                                        float s_relu, float s_next)
{
#pragma clang fp contract(off)
    float y = (float)s * fscale;
    y = y * inv;
    y = y + beta;
    float r = rintf(y / s_relu);
    r = fminf(fmaxf(r, 0.f), 15.f);
    float v = r * s_relu;
    float r2 = rintf(v / s_next);
    r2 = fminf(fmaxf(r2, -8.f), 7.f);
    return (int8_t)(int)r2;
}

// ---------------------------------------------------------------------------
// Per-tensor weight max-abs. grid (16, 9)
// ---------------------------------------------------------------------------
struct WPtrs { const float* w[9]; int n[9]; };

__global__ __launch_bounds__(256) void k_wmax(WPtrs a, unsigned* __restrict__ smax)
{
    const int t = blockIdx.y;
    const int n = a.n[t];
    const float* w = a.w[t];
    float m = 0.f;
    for (int i = blockIdx.x * 256 + threadIdx.x; i < n; i += 16 * 256)
        m = fmaxf(m, fabsf(w[i]));
#pragma unroll
    for (int off = 32; off > 0; off >>= 1) m = fmaxf(m, __shfl_down(m, off));
    __shared__ float red[4];
    if ((threadIdx.x & 63) == 0) red[threadIdx.x >> 6] = m;
    __syncthreads();
    if (threadIdx.x == 0) {
        m = fmaxf(fmaxf(red[0], red[1]), fmaxf(red[2], red[3]));
        atomicMax(smax + t, __float_as_uint(m));
    }
}

// ---------------------------------------------------------------------------
// Pack kernel:
//  seg B   : conv weights -> MFMA B-fragment order (52992 dwords)
//  seg HEAD: head weights -> [cig*36+co] dwords (576)
//  seg BN  : inv/beta (8*128 floats)
//  seg INQ : input double fake-quant -> NHWC int8x4 (CIG=1)
// ---------------------------------------------------------------------------
struct PackArgs {
    const float* w[9];
    const float* bn[8];
    const float* x;
    const float* scales;
    const unsigned* smax;
    int* qw;
    float* bnp;
    int* a0;
};

#define NB_B    207
#define NB_HEAD 3
#define NB_BN   2
#define NB_INQ  12800

__global__ __launch_bounds__(256) void k_pack(PackArgs a)
{
#pragma clang fp contract(off)
    const int blk = blockIdx.x;
    if (blk < NB_B) {
        const int u = blk * 256 + threadIdx.x;   // 0..52991 (exact)
        const int bcum[9] = {0, 256, 1792, 6912, 16128, 25344, 34560, 43776, 52992};
        const int CIGA[8] = {1, 4, 8, 16, 16, 16, 16, 16};
        const int COA[8]  = {16, 32, 64, 64, 64, 64, 64, 64};
        const int NTA[8]  = {1, 2, 4, 4, 4, 4, 4, 4};
        const int CINA[8] = {3, 16, 32, 64, 64, 64, 64, 64};
        int L = 0;
        while (u >= bcum[L + 1]) ++L;
        const int rem = u - bcum[L];
        const int d = rem & 3;
        const int lane = (rem >> 2) & 63;
        const int gnt = rem >> 8;
        const int NT = NTA[L];
        const int nt = gnt % NT;
        const int g = gnt / NT;
        const int CIG = CIGA[L], CIN = CINA[L], CO = COA[L];
        const int TG = 16 / CIG;
        const int n = nt * 16 + (lane & 15);
        const float s = __uint_as_float(a.smax[L]) / 7.0f;
        const float* w = a.w[L];
        unsigned dw = 0;
        for (int jb = 0; jb < 4; ++jb) {
            const int k = 16 * (lane >> 4) + 4 * d + jb;
            const int tap = g * TG + k / (4 * CIG);
            const int ci = k % (4 * CIG);
            int qv = 0;
            if (tap < 9 && ci < CIN && n < CO) {
                float rr = rintf(w[(n * CIN + ci) * 9 + tap] / s);
                rr = fminf(fmaxf(rr, -7.f), 7.f);
                qv = (int)rr;
            }
            dw |= ((unsigned)(qv & 0xff)) << (8 * jb);
        }
        a.qw[u] = (int)dw;
    } else if (blk < NB_B + NB_HEAD) {
        const int u = (blk - NB_B) * 256 + threadIdx.x;
        if (u >= 576) return;
        const int co = u % 36;
        const int cig = u / 36;
        const float s = __uint_as_float(a.smax[8]) / 7.0f;
        const float* w = a.w[8];
        unsigned dw = 0;
        for (int jb = 0; jb < 4; ++jb) {
            const int ci = 4 * cig + jb;
            float rr = rintf(w[co * 64 + ci] / s);
            rr = fminf(fmaxf(rr, -7.f), 7.f);
            dw |= ((unsigned)(((int)rr) & 0xff)) << (8 * jb);
        }
        a.qw[52992 + u] = (int)dw;
    } else if (blk < NB_B + NB_HEAD + NB_BN) {
        const int id = (blk - NB_B - NB_HEAD) * 256 + threadIdx.x;
        if (id >= 512) return;
        const int l = id >> 6, c = id & 63;
        const int C[8] = {16, 32, 64, 64, 64, 64, 64, 64};
        if (c < C[l]) {
            const float* bn = a.bn[l];
            const int Cl = C[l];
            float g = bn[c], b = bn[Cl + c], m = bn[2 * Cl + c], v = bn[3 * Cl + c];
            float inv = g / sqrtf(v + EPSV);
            float mi = m * inv;
            a.bnp[l * 128 + c] = inv;
            a.bnp[l * 128 + 64 + c] = b - mi;
        }
    } else {
        const int p = (blk - NB_B - NB_HEAD - NB_BN) * 256 + threadIdx.x;  // < 3,276,800
        const int HW = 320 * 640;
        const int b = p / HW;
        const int rest = p - b * HW;
        const float s0 = a.scales[0], s1 = a.scales[1];
        unsigned dw = 0;
#pragma unroll
        for (int ci = 0; ci < 3; ++ci) {
            float xv = a.x[(b * 3 + ci) * HW + rest];
            float r = rintf(xv / s0);
            r = fminf(fmaxf(r, -8.f), 7.f);
            float v = r * s0;
            float r2 = rintf(v / s1);
            r2 = fminf(fmaxf(r2, -8.f), 7.f);
            dw |= ((unsigned)(((int)r2) & 0xff)) << (8 * ci);
        }
        a.a0[p] = (int)dw;
    }
}

// ---------------------------------------------------------------------------
// MFMA conv block. NHWC int8 in/out (CIG dwords per px in, CO bytes per px out).
// Pooled:  M-row m = 4*px_sub + pool_op; wave = 1 out row, XL strips of 4 px.
// Nonpool: M-row m = out px (strip of 16); 4 waves = 2 rows x 2 nt-halves.
// B prepacked in fragment order: dword index ((g*NT+nt)*64 + lane)*4 + d.
// ---------------------------------------------------------------------------
template <int CIG, int CO, bool POOL, int H, int W, int XL, int NROWS>
__global__ __launch_bounds__(256) void k_mconv(
    const int8_t* __restrict__ in, int8_t* __restrict__ out,
    const int* __restrict__ bfrag, const float* __restrict__ scales,
    const unsigned* __restrict__ smax, const float* __restrict__ bnp,
    int layer, int sin_idx, int srelu_idx, int snext_idx)
{
    constexpr int NT = CO / 16;
    constexpr int TG = 16 / CIG;              // taps per K=64 group
    constexpr int NG = (9 + TG - 1) / TG;     // K groups
    constexpr int WPR = POOL ? 1 : 2;         // waves per row
    constexpr int NTW = POOL ? NT : NT / 2;   // nt per wave
    constexpr int OPW = POOL ? 4 : 16;        // out px per strip
    constexpr int S = POOL ? 2 : 1;
    constexpr int TLH = S * NROWS + 2;
    constexpr int TLW = S * OPW * XL + 2;
    constexpr int TILE_DW = TLH * TLW * CIG;
    constexpr bool BLDS = (CIG >= 8);
    constexpr int BDW = NG * NT * 256;
    constexpr int Ho = POOL ? H / 2 : H;
    constexpr int Wo = POOL ? W / 2 : W;
    static_assert(WPR * NROWS == 4, "4 waves per block");
    static_assert(POOL || CIG == 16, "nonpool path assumes CIG=16");

    __shared__ int tile[TILE_DW];
    __shared__ int bsh[BLDS ? BDW : 1];
    __shared__ float bnl[128];

    const int b = blockIdx.z;
    const int py0 = blockIdx.y * NROWS;
    const int px0 = blockIdx.x * (OPW * XL);
    const int ty0 = S * py0 - 1;
    const int tx0 = S * px0 - 1;
    const int* gin = (const int*)in;

    // stage zero-padded input tile (cig fastest -> coalesced)
    for (int i = threadIdx.x; i < TILE_DW; i += 256) {
        const int cig = i % CIG;
        const int rest = i / CIG;
        const int lx = rest % TLW;
        const int ly = rest / TLW;
        const int gy = ty0 + ly, gx = tx0 + lx;
        int v = 0;
        if ((unsigned)gy < (unsigned)H && (unsigned)gx < (unsigned)W)
            v = gin[((b * H + gy) * W + gx) * CIG + cig];
        tile[i] = v;
    }
    if (BLDS)
        for (int i = threadIdx.x; i < BDW; i += 256) bsh[i] = bfrag[i];
    if (threadIdx.x < 128) bnl[threadIdx.x] = bnp[layer * 128 + threadIdx.x];

    const int lane = threadIdx.x & 63;
    const int wv = threadIdx.x >> 6;
    v4i breg[BLDS ? 1 : NG * NT];
    if (!BLDS) {
#pragma unroll
        for (int i = 0; i < NG * NT; ++i)
            breg[i] = *(const v4i*)&bfrag[(i * 64 + lane) * 4];
    }
    __syncthreads();

    const int q = lane >> 4;
    const int m = lane & 15;

    const float swv = __uint_as_float(smax[layer]) / 7.0f;
    const float fscale = scales[sin_idx] * swv;
    const float s_relu = scales[srelu_idx];
    const float s_next = scales[snext_idx];

    // per-lane A geometry
    int lyb, lxb0, wrow, nt0;
    if (POOL) {
        const int px_sub = m >> 2;
        const int op = m & 3;
        wrow = wv;
        nt0 = 0;
        lyb = 2 * wrow + (op >> 1);
        lxb0 = 2 * px_sub + (op & 1);
    } else {
        wrow = wv >> 1;
        nt0 = (wv & 1) * NTW;
        lyb = wrow;
        lxb0 = m;
    }

    for (int xs = 0; xs < XL; ++xs) {
        v4i acc[NTW];
#pragma unroll
        for (int j = 0; j < NTW; ++j) acc[j] = (v4i){0, 0, 0, 0};

#pragma unroll
        for (int g = 0; g < NG; ++g) {
            v4i af;
            if constexpr (CIG == 16) {
                const int ky = (g * 11) >> 5;
                const int kx = g - 3 * ky;
                int addr;
                if (POOL) addr = ((lyb + ky) * TLW + (8 * xs + lxb0 + kx)) * 16 + 4 * q;
                else      addr = ((lyb + ky) * TLW + (lxb0 + kx)) * 16 + 4 * q;
                af = *(const v4i*)&tile[addr];
            } else if constexpr (CIG == 8) {
                int t = 2 * g + (q >> 1); t = min(t, 8);
                const int ky = (t * 11) >> 5;
                const int kx = t - 3 * ky;
                const int addr = ((lyb + ky) * TLW + (8 * xs + lxb0 + kx)) * 8 + 4 * (q & 1);
                af = *(const v4i*)&tile[addr];
            } else if constexpr (CIG == 4) {
                int t = 4 * g + q; t = min(t, 8);
                const int ky = (t * 11) >> 5;
                const int kx = t - 3 * ky;
                const int addr = ((lyb + ky) * TLW + (8 * xs + lxb0 + kx)) * 4;
                af = *(const v4i*)&tile[addr];
            } else {  // CIG == 1
#pragma unroll
                for (int d = 0; d < 4; ++d) {
                    int t = 4 * q + d; t = min(t, 8);
                    const int ky = (t * 11) >> 5;
                    const int kx = t - 3 * ky;
                    af[d] = tile[(lyb + ky) * TLW + (8 * xs + lxb0 + kx)];
                }
            }
#pragma unroll
            for (int j = 0; j < NTW; ++j) {
                const int nt = nt0 + j;
                v4i bf;
                if (BLDS) bf = *(const v4i*)&bsh[((g * NT + nt) * 64 + lane) * 4];
                else      bf = breg[g * NT + nt];
                acc[j] = mfma16(af, bf, acc[j]);
            }
        }

        if (POOL) {
            // lane holds out px_sub = q, col = m; regs = 4 pool candidates
            const int py = py0 + wrow;
            const int px = px0 + 4 * xs + q;
            int8_t* po = out + ((size_t)((b * Ho + py) * Wo + px)) * CO + m;
#pragma unroll
            for (int j = 0; j < NTW; ++j) {
                const int co = j * 16 + m;
                const int s = max(max(acc[j][0], acc[j][1]), max(acc[j][2], acc[j][3]));
                po[j * 16] = q_epi(s, fscale, bnl[co], bnl[64 + co], s_relu, s_next);
            }
        } else {
            // lane holds px = px0 + 4q + reg, col = m
            const int py = py0 + wrow;
#pragma unroll
            for (int j = 0; j < NTW; ++j) {
                const int co = (nt0 + j) * 16 + m;
                const float inv = bnl[co], beta = bnl[64 + co];
#pragma unroll
                for (int r = 0; r < 4; ++r) {
                    const int px = px0 + 4 * q + r;
                    if (px < Wo)
                        out[((size_t)((b * Ho + py) * Wo + px)) * CO + co] =
                            q_epi(acc[j][r], fscale, inv, beta, s_relu, s_next);
                }
            }
        }
    }
}

// ---------------------------------------------------------------------------
// Head: 1x1 conv 64->36 + bias, fp32 NCHW out. grid (4, 16)
// ---------------------------------------------------------------------------
__global__ __launch_bounds__(256) void k_head(
    const int8_t* __restrict__ in,   // NHWC [16][20][40][64]
    float* __restrict__ out,         // NCHW [16][36][800]
    const int* __restrict__ wq,      // [cig*36 + co]
    const float* __restrict__ scales,
    const unsigned* __restrict__ smax,
    const float* __restrict__ b9)
{
#pragma clang fp contract(off)
    __shared__ int wl[576];
    for (int i = threadIdx.x; i < 576; i += 256) wl[i] = wq[i];
    __syncthreads();
    const int px = blockIdx.x * 256 + threadIdx.x;
    const int b = blockIdx.y;
    if (px >= 800) return;
    const int* ip = (const int*)in + (size_t)(b * 800 + px) * 16;
    int p[16];
#pragma unroll
    for (int c4 = 0; c4 < 4; ++c4) *(int4*)&p[4 * c4] = *(const int4*)&ip[4 * c4];
    const float fs = scales[9] * (__uint_as_float(smax[8]) / 7.0f);
    for (int co = 0; co < 36; ++co) {
        int acc = 0;
#pragma unroll
        for (int cig = 0; cig < 16; ++cig) acc = dot4(p[cig], wl[cig * 36 + co], acc);
        float y = (float)acc * fs;
        out[(size_t)(b * 36 + co) * 800 + px] = y + b9[co];
    }
}

// ---------------------------------------------------------------------------
// Launch
// ---------------------------------------------------------------------------
extern "C" void kernel_launch(void* const* d_in, const int* in_sizes, int n_in,
                              void* d_out, int out_size, void* d_ws, size_t ws_size,
                              hipStream_t stream)
{
    const float* x = (const float*)d_in[0];
    const float* w[9];
    for (int i = 0; i < 9; i++) w[i] = (const float*)d_in[1 + i];
    const float* b9 = (const float*)d_in[10];
    const float* bn[8];
    for (int i = 0; i < 8; i++) bn[i] = (const float*)d_in[11 + i];
    const float* scales = (const float*)d_in[19];

    int8_t* base = (int8_t*)d_ws;
    int8_t* bufA = base;                             // 13,107,200 B
    int8_t* bufB = base + 13107200;                  // 13,107,200 B
    int*     qw  = (int*)(base + 26214400);          // 53568 dwords
    unsigned* smax = (unsigned*)(base + 26429440);   // 9
    float*   bnp = (float*)(base + 26429952);        // 1024 floats

    static const int wn[9] = {432, 4608, 18432, 36864, 36864, 36864, 36864, 36864, 2304};
    static const int bo[8] = {0, 256, 1792, 6912, 16128, 25344, 34560, 43776};

    hipMemsetAsync(smax, 0, 9 * sizeof(unsigned), stream);

    WPtrs wp;
    for (int i = 0; i < 9; i++) { wp.w[i] = w[i]; wp.n[i] = wn[i]; }
    k_wmax<<<dim3(16, 9), 256, 0, stream>>>(wp, smax);

    PackArgs pa;
    for (int i = 0; i < 9; i++) pa.w[i] = w[i];
    for (int i = 0; i < 8; i++) pa.bn[i] = bn[i];
    pa.x = x; pa.scales = scales; pa.smax = smax;
    pa.qw = qw; pa.bnp = bnp; pa.a0 = (int*)bufA;
    k_pack<<<NB_B + NB_HEAD + NB_BN + NB_INQ, 256, 0, stream>>>(pa);

    // L0: CIG=1, CO=16, pool, conv 320x640 -> out 160x320
    k_mconv<1, 16, true, 320, 640, 8, 4><<<dim3(10, 40, 16), 256, 0, stream>>>(
        bufA, bufB, qw + bo[0], scales, smax, bnp, 0, 1, 10, 2);
    // L1: CIG=4, CO=32, pool, conv 160x320 -> out 80x160
    k_mconv<4, 32, true, 160, 320, 4, 4><<<dim3(10, 20, 16), 256, 0, stream>>>(
        bufB, bufA, qw + bo[1], scales, smax, bnp, 1, 2, 11, 3);
    // L2: CIG=8, CO=64, pool, conv 80x160 -> out 40x80
    k_mconv<8, 64, true, 80, 160, 2, 4><<<dim3(10, 10, 16), 256, 0, stream>>>(
        bufA, bufB, qw + bo[2], scales, smax, bnp, 2, 3, 12, 4);
    // L3: CIG=16, CO=64, pool, conv 40x80 -> out 20x40
    k_mconv<16, 64, true, 40, 80, 1, 4><<<dim3(10, 5, 16), 256, 0, stream>>>(
        bufB, bufA, qw + bo[3], scales, smax, bnp, 3, 4, 13, 5);
    // L4-7: CIG=16, CO=64, nonpool, 20x40
    k_mconv<16, 64, false, 20, 40, 1, 2><<<dim3(3, 10, 16), 256, 0, stream>>>(
        bufA, bufB, qw + bo[4], scales, smax, bnp, 4, 5, 14, 6);
    k_mconv<16, 64, false, 20, 40, 1, 2><<<dim3(3, 10, 16), 256, 0, stream>>>(
        bufB, bufA, qw + bo[5], scales, smax, bnp, 5, 6, 15, 7);
    k_mconv<16, 64, false, 20, 40, 1, 2><<<dim3(3, 10, 16), 256, 0, stream>>>(
        bufA, bufB, qw + bo[6], scales, smax, bnp, 6, 7, 16, 8);
    k_mconv<16, 64, false, 20, 40, 1, 2><<<dim3(3, 10, 16), 256, 0, stream>>>(
        bufB, bufA, qw + bo[7], scales, smax, bnp, 7, 8, 17, 9);

    k_head<<<dim3(4, 16), 256, 0, stream>>>(
        bufA, (float*)d_out, qw + 52992, scales, smax, b9);

    (void)in_sizes; (void)n_in; (void)out_size; (void)ws_size;
}

// Round 4
// 216.650 us; speedup vs baseline: 15.2725x; 1.0209x over previous
//
#include <hip/hip_runtime.h>
#include <stdint.h>

#define EPSV 1e-5f

typedef int v4i __attribute__((ext_vector_type(4)));

__device__ __forceinline__ v4i mfma16(v4i a, v4i b, v4i c) {
    return __builtin_amdgcn_mfma_i32_16x16x64_i8(a, b, c, 0, 0, 0);
}

// epilogue: BN + ReLU-u4-quant + requant to next layer's signed-4 code.
// (called on the pool-max of raw int accs; valid since inv>0 => monotone)
__device__ __forceinline__ int8_t q_epi(int s, float fscale, float inv, float beta,
                                        float s_relu, float s_next)
{
#pragma clang fp contract(off)
    float y = (float)s * fscale;
    y = y * inv;
    y = y + beta;
    float r = rintf(y / s_relu);
    r = fminf(fmaxf(r, 0.f), 15.f);
    float v = r * s_relu;
    float r2 = rintf(v / s_next);
    r2 = fminf(fmaxf(r2, -8.f), 7.f);
    return (int8_t)(int)r2;
}

// ---------------------------------------------------------------------------
// Per-tensor weight max-abs. grid (16, 9)
// ---------------------------------------------------------------------------
struct WPtrs { const float* w[9]; int n[9]; };

__global__ __launch_bounds__(256) void k_wmax(WPtrs a, unsigned* __restrict__ smax)
{
    const int t = blockIdx.y;
    const int n = a.n[t];
    const float* w = a.w[t];
    float m = 0.f;
    for (int i = blockIdx.x * 256 + threadIdx.x; i < n; i += 16 * 256)
        m = fmaxf(m, fabsf(w[i]));
#pragma unroll
    for (int off = 32; off > 0; off >>= 1) m = fmaxf(m, __shfl_down(m, off));
    __shared__ float red[4];
    if ((threadIdx.x & 63) == 0) red[threadIdx.x >> 6] = m;
    __syncthreads();
    if (threadIdx.x == 0) {
        m = fmaxf(fmaxf(red[0], red[1]), fmaxf(red[2], red[3]));
        atomicMax(smax + t, __float_as_uint(m));
    }
}

// ---------------------------------------------------------------------------
// Pack kernel:
//  seg B    : conv weights -> MFMA B-fragment order (52992 dwords)
//  seg HEADF: head weights -> MFMA B-fragment order, NT=3 (768 dwords)
//  seg BN   : inv/beta (8*128 floats)
// ---------------------------------------------------------------------------
struct PackArgs {
    const float* w[9];
    const float* bn[8];
    const unsigned* smax;
    int* qw;
    float* bnp;
};

#define NB_B    207
#define NB_HEAD 3
#define NB_BN   2

__global__ __launch_bounds__(256) void k_pack(PackArgs a)
{
#pragma clang fp contract(off)
    const int blk = blockIdx.x;
    if (blk < NB_B) {
        const int u = blk * 256 + threadIdx.x;   // 0..52991 (exact)
        const int bcum[9] = {0, 256, 1792, 6912, 16128, 25344, 34560, 43776, 52992};
        const int CIGA[8] = {1, 4, 8, 16, 16, 16, 16, 16};
        const int COA[8]  = {16, 32, 64, 64, 64, 64, 64, 64};
        const int NTA[8]  = {1, 2, 4, 4, 4, 4, 4, 4};
        const int CINA[8] = {3, 16, 32, 64, 64, 64, 64, 64};
        int L = 0;
        while (u >= bcum[L + 1]) ++L;
        const int rem = u - bcum[L];
        const int d = rem & 3;
        const int lane = (rem >> 2) & 63;
        const int gnt = rem >> 8;
        const int NT = NTA[L];
        const int nt = gnt % NT;
        const int g = gnt / NT;
        const int CIG = CIGA[L], CIN = CINA[L], CO = COA[L];
        const int TG = 16 / CIG;
        const int n = nt * 16 + (lane & 15);
        const float s = __uint_as_float(a.smax[L]) / 7.0f;
        const float* w = a.w[L];
        unsigned dw = 0;
        for (int jb = 0; jb < 4; ++jb) {
            const int k = 16 * (lane >> 4) + 4 * d + jb;
            const int tap = g * TG + k / (4 * CIG);
            const int ci = k % (4 * CIG);
            int qv = 0;
            if (tap < 9 && ci < CIN && n < CO) {
                float rr = rintf(w[(n * CIN + ci) * 9 + tap] / s);
                rr = fminf(fmaxf(rr, -7.f), 7.f);
                qv = (int)rr;
            }
            dw |= ((unsigned)(qv & 0xff)) << (8 * jb);
        }
        a.qw[u] = (int)dw;
    } else if (blk < NB_B + NB_HEAD) {
        const int uh = (blk - NB_B) * 256 + threadIdx.x;  // 0..767 (exact)
        const int d = uh & 3;
        const int lane = (uh >> 2) & 63;
        const int nt = uh >> 8;                            // 0..2
        const int n = nt * 16 + (lane & 15);
        const float s = __uint_as_float(a.smax[8]) / 7.0f;
        const float* w = a.w[8];
        unsigned dw = 0;
        for (int jb = 0; jb < 4; ++jb) {
            const int ci = 16 * (lane >> 4) + 4 * d + jb;   // K=64 = cin
            int qv = 0;
            if (n < 36) {
                float rr = rintf(w[n * 64 + ci] / s);
                rr = fminf(fmaxf(rr, -7.f), 7.f);
                qv = (int)rr;
            }
            dw |= ((unsigned)(qv & 0xff)) << (8 * jb);
        }
        a.qw[52992 + uh] = (int)dw;
    } else {
        const int id = (blk - NB_B - NB_HEAD) * 256 + threadIdx.x;
        if (id >= 512) return;
        const int l = id >> 6, c = id & 63;
        const int C[8] = {16, 32, 64, 64, 64, 64, 64, 64};
        if (c < C[l]) {
            const float* bn = a.bn[l];
            const int Cl = C[l];
            float g = bn[c], b = bn[Cl + c], m = bn[2 * Cl + c], v = bn[3 * Cl + c];
            float inv = g / sqrtf(v + EPSV);
            float mi = m * inv;
            a.bnp[l * 128 + c] = inv;
            a.bnp[l * 128 + 64 + c] = b - mi;
        }
    }
}

// ---------------------------------------------------------------------------
// L0 fused: double fake-quant of fp32 x (NCHW) during tile staging + MFMA conv
// 3->16ch + BN/ReLU-quant/pool/requant. out NHWC [16][160][320][16].
// grid (10, 40, 16); tile 10x66 px, CIG=1, NG=1, NT=1, XL=8.
// ---------------------------------------------------------------------------
__global__ __launch_bounds__(256) void k_conv0(
    const float* __restrict__ x, int8_t* __restrict__ out,
    const int* __restrict__ bfrag, const float* __restrict__ scales,
    const unsigned* __restrict__ smax, const float* __restrict__ bnp)
{
#pragma clang fp contract(off)
    __shared__ int tile[660];        // 10 * 66
    __shared__ float bnl[128];

    const int b = blockIdx.z;
    const int py0 = blockIdx.y * 4;
    const int px0 = blockIdx.x * 32;
    const int ty0 = 2 * py0 - 1;
    const int tx0 = 2 * px0 - 1;
    const float s0 = scales[0], s1 = scales[1];

    for (int i = threadIdx.x; i < 660; i += 256) {
        const int ly = i / 66;
        const int lx = i - ly * 66;
        const int gy = ty0 + ly, gx = tx0 + lx;
        int v = 0;
        if ((unsigned)gy < 320u && (unsigned)gx < 640u) {
#pragma unroll
            for (int ci = 0; ci < 3; ++ci) {
                float xv = x[((size_t)(b * 3 + ci) * 320 + gy) * 640 + gx];
                float r = rintf(xv / s0);
                r = fminf(fmaxf(r, -8.f), 7.f);
                float vv = r * s0;
                float r2 = rintf(vv / s1);
                r2 = fminf(fmaxf(r2, -8.f), 7.f);
                v |= ((int)r2 & 0xff) << (8 * ci);
            }
        }
        tile[i] = v;
    }
    if (threadIdx.x < 128) bnl[threadIdx.x] = bnp[threadIdx.x];

    const int lane = threadIdx.x & 63;
    const int wv = threadIdx.x >> 6;
    const v4i bfv = *(const v4i*)&bfrag[lane * 4];
    __syncthreads();

    const int q = lane >> 4;
    const int m = lane & 15;
    const int px_sub = m >> 2;
    const int op = m & 3;
    const int lyb = 2 * wv + (op >> 1);
    const int lxb0 = 2 * px_sub + (op & 1);

    const float sw = __uint_as_float(smax[0]) / 7.0f;
    const float fscale = scales[1] * sw;
    const float s_relu = scales[10];
    const float s_next = scales[2];
    const float inv = bnl[m];
    const float beta = bnl[64 + m];
    const int py = py0 + wv;

    for (int xs = 0; xs < 8; ++xs) {
        v4i af;
#pragma unroll
        for (int d = 0; d < 4; ++d) {
            int t = 4 * q + d; t = min(t, 8);
            const int ky = (t * 11) >> 5;
            const int kx = t - 3 * ky;
            af[d] = tile[(lyb + ky) * 66 + 8 * xs + lxb0 + kx];
        }
        v4i acc = mfma16(af, bfv, (v4i){0, 0, 0, 0});
        const int px = px0 + 4 * xs + q;
        const int s = max(max(acc[0], acc[1]), max(acc[2], acc[3]));
        out[((size_t)((b * 160 + py) * 320 + px)) * 16 + m] =
            q_epi(s, fscale, inv, beta, s_relu, s_next);
    }
}

// ---------------------------------------------------------------------------
// MFMA conv block. NHWC int8 in/out. B fragments read from global (L2-hot);
// preloaded to regs when small. FUSED: append 1x1 head (64->36) + bias and
// write fp32 NCHW d_out directly (no global code write).
// ---------------------------------------------------------------------------
template <int CIG, int CO, bool POOL, int H, int W, int XL, int NROWS, bool FUSED>
__global__ __launch_bounds__(256) void k_mconv(
    const int8_t* __restrict__ in, int8_t* __restrict__ out,
    const int* __restrict__ bfrag, const float* __restrict__ scales,
    const unsigned* __restrict__ smax, const float* __restrict__ bnp,
    int layer, int sin_idx, int srelu_idx, int snext_idx,
    const int* __restrict__ hfrag, const float* __restrict__ b9,
    float* __restrict__ dout)
{
    constexpr int NT = CO / 16;
    constexpr int TG = 16 / CIG;              // taps per K=64 group
    constexpr int NG = (9 + TG - 1) / TG;     // K groups
    constexpr int WPR = POOL ? 1 : 2;         // waves per row
    constexpr int NTW = POOL ? NT : NT / 2;   // nt per wave
    constexpr int OPW = POOL ? 4 : 16;        // out px per strip
    constexpr int S = POOL ? 2 : 1;
    constexpr int TLH = S * NROWS + 2;
    constexpr int TLW = S * OPW * XL + 2;
    constexpr int TILE_DW = TLH * TLW * CIG;
    constexpr bool PRELOAD = (NG * NT <= 8);
    constexpr int Ho = POOL ? H / 2 : H;
    constexpr int Wo = POOL ? W / 2 : W;
    static_assert(WPR * NROWS == 4, "4 waves per block");
    static_assert(POOL || CIG == 16, "nonpool path assumes CIG=16");
    static_assert(!FUSED || (!POOL && XL == 1 && NROWS == 2), "fused head shape");

    __shared__ int tile[TILE_DW];
    __shared__ float bnl[128];
    __shared__ int code_dw[FUSED ? 512 : 1];  // 32 px x 16 dw, A-frag order

    const int b = blockIdx.z;
    const int py0 = blockIdx.y * NROWS;
    const int px0 = blockIdx.x * (OPW * XL);
    const int ty0 = S * py0 - 1;
    const int tx0 = S * px0 - 1;
    const int* gin = (const int*)in;

    // stage zero-padded input tile (cig fastest -> coalesced)
    for (int i = threadIdx.x; i < TILE_DW; i += 256) {
        const int cig = i & (CIG - 1);
        const int rest = i / CIG;
        const int lx = rest % TLW;
        const int ly = rest / TLW;
        const int gy = ty0 + ly, gx = tx0 + lx;
        int v = 0;
        if ((unsigned)gy < (unsigned)H && (unsigned)gx < (unsigned)W)
            v = gin[((b * H + gy) * W + gx) * CIG + cig];
        tile[i] = v;
    }
    if (threadIdx.x < 128) bnl[threadIdx.x] = bnp[layer * 128 + threadIdx.x];

    const int lane = threadIdx.x & 63;
    const int wv = threadIdx.x >> 6;
    v4i breg[PRELOAD ? NG * NT : 1];
    if constexpr (PRELOAD) {
#pragma unroll
        for (int i = 0; i < NG * NT; ++i)
            breg[i] = *(const v4i*)&bfrag[(i * 64 + lane) * 4];
    }
    __syncthreads();

    const int q = lane >> 4;
    const int m = lane & 15;

    const float swv = __uint_as_float(smax[layer]) / 7.0f;
    const float fscale = scales[sin_idx] * swv;
    const float s_relu = scales[srelu_idx];
    const float s_next = scales[snext_idx];

    // per-lane A geometry
    int lyb, lxb0, wrow, nt0;
    if (POOL) {
        const int px_sub = m >> 2;
        const int op = m & 3;
        wrow = wv;
        nt0 = 0;
        lyb = 2 * wrow + (op >> 1);
        lxb0 = 2 * px_sub + (op & 1);
    } else {
        wrow = wv >> 1;
        nt0 = (wv & 1) * NTW;
        lyb = wrow;
        lxb0 = m;
    }

    for (int xs = 0; xs < XL; ++xs) {
        v4i acc[NTW];
#pragma unroll
        for (int j = 0; j < NTW; ++j) acc[j] = (v4i){0, 0, 0, 0};

#pragma unroll
        for (int g = 0; g < NG; ++g) {
            v4i af;
            if constexpr (CIG == 16) {
                const int ky = (g * 11) >> 5;
                const int kx = g - 3 * ky;
                int addr;
                if (POOL) addr = ((lyb + ky) * TLW + (8 * xs + lxb0 + kx)) * 16 + 4 * q;
                else      addr = ((lyb + ky) * TLW + (lxb0 + kx)) * 16 + 4 * q;
                af = *(const v4i*)&tile[addr];
            } else if constexpr (CIG == 8) {
                int t = 2 * g + (q >> 1); t = min(t, 8);
                const int ky = (t * 11) >> 5;
                const int kx = t - 3 * ky;
                const int addr = ((lyb + ky) * TLW + (8 * xs + lxb0 + kx)) * 8 + 4 * (q & 1);
                af = *(const v4i*)&tile[addr];
            } else if constexpr (CIG == 4) {
                int t = 4 * g + q; t = min(t, 8);
                const int ky = (t * 11) >> 5;
                const int kx = t - 3 * ky;
                const int addr = ((lyb + ky) * TLW + (8 * xs + lxb0 + kx)) * 4;
                af = *(const v4i*)&tile[addr];
            } else {  // CIG == 1
#pragma unroll
                for (int d = 0; d < 4; ++d) {
                    int t = 4 * q + d; t = min(t, 8);
                    const int ky = (t * 11) >> 5;
                    const int kx = t - 3 * ky;
                    af[d] = tile[(lyb + ky) * TLW + (8 * xs + lxb0 + kx)];
                }
            }
#pragma unroll
            for (int j = 0; j < NTW; ++j) {
                v4i bf;
                if constexpr (PRELOAD) bf = breg[g * NT + nt0 + j];
                else bf = *(const v4i*)&bfrag[((g * NT + nt0 + j) * 64 + lane) * 4];
                acc[j] = mfma16(af, bf, acc[j]);
            }
        }

        if (POOL) {
            // lane holds out px_sub = q, col = m; regs = 4 pool candidates
            const int py = py0 + wrow;
            const int px = px0 + 4 * xs + q;
            int8_t* po = out + ((size_t)((b * Ho + py) * Wo + px)) * CO + m;
#pragma unroll
            for (int j = 0; j < NTW; ++j) {
                const int co = j * 16 + m;
                const int s = max(max(acc[j][0], acc[j][1]), max(acc[j][2], acc[j][3]));
                po[j * 16] = q_epi(s, fscale, bnl[co], bnl[64 + co], s_relu, s_next);
            }
        } else {
            // lane holds px = px0 + 4q + reg, col = m
            const int py = py0 + wrow;
#pragma unroll
            for (int j = 0; j < NTW; ++j) {
                const int co = (nt0 + j) * 16 + m;
                const float inv = bnl[co], beta = bnl[64 + co];
#pragma unroll
                for (int r = 0; r < 4; ++r) {
                    const int px = px0 + 4 * q + r;
                    const int8_t cb = q_epi(acc[j][r], fscale, inv, beta, s_relu, s_next);
                    if constexpr (FUSED) {
                        ((int8_t*)code_dw)[(wrow * 16 + 4 * q + r) * 64 + co] = cb;
                    } else {
                        if (px < Wo)
                            out[((size_t)((b * Ho + py) * Wo + px)) * CO + co] = cb;
                    }
                }
            }
        }
    }

    if constexpr (FUSED) {
        __syncthreads();
        if (wv < 2) {
#pragma clang fp contract(off)
            // head: M-tile = wv (px p_local = wv*16 + row), K=64, N=48 (36 used)
            const v4i ha = *(const v4i*)&code_dw[(wv * 16 + m) * 16 + 4 * q];
            const float fs = scales[9] * (__uint_as_float(smax[8]) / 7.0f);
            const int py2 = py0 + wv;
#pragma unroll
            for (int nt = 0; nt < 3; ++nt) {
                const v4i hb = *(const v4i*)&hfrag[(nt * 64 + lane) * 4];
                const v4i hacc = mfma16(ha, hb, (v4i){0, 0, 0, 0});
                const int co = nt * 16 + m;
                if (co < 36) {
                    const float bias = b9[co];
#pragma unroll
                    for (int r = 0; r < 4; ++r) {
                        const int px = px0 + 4 * q + r;
                        if (px < 40) {
                            float y = (float)hacc[r] * fs;
                            dout[((size_t)(b * 36 + co)) * 800 + py2 * 40 + px] = y + bias;
                        }
                    }
                }
            }
        }
    }
}

// ---------------------------------------------------------------------------
// Launch
// ---------------------------------------------------------------------------
extern "C" void kernel_launch(void* const* d_in, const int* in_sizes, int n_in,
                              void* d_out, int out_size, void* d_ws, size_t ws_size,
                              hipStream_t stream)
{
    const float* x = (const float*)d_in[0];
    const float* w[9];
    for (int i = 0; i < 9; i++) w[i] = (const float*)d_in[1 + i];
    const float* b9 = (const float*)d_in[10];
    const float* bn[8];
    for (int i = 0; i < 8; i++) bn[i] = (const float*)d_in[11 + i];
    const float* scales = (const float*)d_in[19];

    int8_t* base = (int8_t*)d_ws;
    int8_t* bufA = base;                             // 13,107,200 B
    int8_t* bufB = base + 13107200;                  // 13,107,200 B
    int*     qw  = (int*)(base + 26214400);          // 53760 dwords
    unsigned* smax = (unsigned*)(base + 26429440);   // 9
    float*   bnp = (float*)(base + 26429952);        // 1024 floats

    static const int wn[9] = {432, 4608, 18432, 36864, 36864, 36864, 36864, 36864, 2304};
    static const int bo[8] = {0, 256, 1792, 6912, 16128, 25344, 34560, 43776};

    hipMemsetAsync(smax, 0, 9 * sizeof(unsigned), stream);

    WPtrs wp;
    for (int i = 0; i < 9; i++) { wp.w[i] = w[i]; wp.n[i] = wn[i]; }
    k_wmax<<<dim3(16, 9), 256, 0, stream>>>(wp, smax);

    PackArgs pa;
    for (int i = 0; i < 9; i++) pa.w[i] = w[i];
    for (int i = 0; i < 8; i++) pa.bn[i] = bn[i];
    pa.smax = smax; pa.qw = qw; pa.bnp = bnp;
    k_pack<<<NB_B + NB_HEAD + NB_BN, 256, 0, stream>>>(pa);

    // L0 (fused input double-quant): fp32 x -> NHWC codes, out bufB
    k_conv0<<<dim3(10, 40, 16), 256, 0, stream>>>(
        x, bufB, qw + bo[0], scales, smax, bnp);

    // L1: CIG=4, CO=32, pool, 160x320 -> 80x160
    k_mconv<4, 32, true, 160, 320, 4, 4, false><<<dim3(10, 20, 16), 256, 0, stream>>>(
        bufB, bufA, qw + bo[1], scales, smax, bnp, 1, 2, 11, 3, nullptr, nullptr, nullptr);
    // L2: CIG=8, CO=64, pool, 80x160 -> 40x80
    k_mconv<8, 64, true, 80, 160, 2, 4, false><<<dim3(10, 10, 16), 256, 0, stream>>>(
        bufA, bufB, qw + bo[2], scales, smax, bnp, 2, 3, 12, 4, nullptr, nullptr, nullptr);
    // L3: CIG=16, CO=64, pool, 40x80 -> 20x40
    k_mconv<16, 64, true, 40, 80, 1, 4, false><<<dim3(10, 5, 16), 256, 0, stream>>>(
        bufB, bufA, qw + bo[3], scales, smax, bnp, 3, 4, 13, 5, nullptr, nullptr, nullptr);
    // L4-6: CIG=16, CO=64, nonpool, 20x40
    k_mconv<16, 64, false, 20, 40, 1, 2, false><<<dim3(3, 10, 16), 256, 0, stream>>>(
        bufA, bufB, qw + bo[4], scales, smax, bnp, 4, 5, 14, 6, nullptr, nullptr, nullptr);
    k_mconv<16, 64, false, 20, 40, 1, 2, false><<<dim3(3, 10, 16), 256, 0, stream>>>(
        bufB, bufA, qw + bo[5], scales, smax, bnp, 5, 6, 15, 7, nullptr, nullptr, nullptr);
    k_mconv<16, 64, false, 20, 40, 1, 2, false><<<dim3(3, 10, 16), 256, 0, stream>>>(
        bufA, bufB, qw + bo[6], scales, smax, bnp, 6, 7, 16, 8, nullptr, nullptr, nullptr);
    // L7 + fused 1x1 head (64->36) + bias -> fp32 NCHW d_out
    k_mconv<16, 64, false, 20, 40, 1, 2, true><<<dim3(3, 10, 16), 256, 0, stream>>>(
        bufB, bufA, qw + bo[7], scales, smax, bnp, 7, 8, 17, 9,
        qw + 52992, b9, (float*)d_out);

    (void)in_sizes; (void)n_in; (void)out_size; (void)ws_size;
}